// Round 1
// baseline (594.816 us; speedup 1.0000x reference)
//
#include <hip/hip_runtime.h>
#include <math.h>

#define BB 4
#define NN 2000
#define KK 5
#define DD 32
#define H1 160
#define HEAD 5
#define HDIM 32
#define MAXNORM 0.996f
#define MINN 1e-15f

__device__ __forceinline__ float artanh_f(float x) {
    x = fminf(fmaxf(x, -1.0f + 1e-7f), 1.0f - 1e-7f);
    return 0.5f * (log1pf(x) - log1pf(-x));
}

__device__ __forceinline__ float wave_sum(float v) {
#pragma unroll
    for (int o = 32; o > 0; o >>= 1) v += __shfl_xor(v, o, 64);
    return v;
}

// ---------------- Kernel A: find one-hot indices in in_nei (320 MB scan) ----
__global__ __launch_bounds__(256) void find_idx_kernel(const float* __restrict__ nei,
                                                       int* __restrict__ idx) {
    const int total4 = BB * NN * KK * NN / 4;  // 20,000,000 float4s
    int stride = gridDim.x * blockDim.x;
    for (int i = blockIdx.x * blockDim.x + threadIdx.x; i < total4; i += stride) {
        float4 v = ((const float4*)nei)[i];
        int f = -1;
        if (v.x > 0.5f) f = 0;
        if (v.y > 0.5f) f = 1;
        if (v.z > 0.5f) f = 2;
        if (v.w > 0.5f) f = 3;
        if (f >= 0) {
            int flat = i * 4 + f;          // < 80M, fits int32
            int row = flat / NN;           // (b*N+n)*K + k
            int m = flat - row * NN;
            idx[row] = m;
        }
    }
}

// ---------------- Kernel B: g[b*N+n, 0:160] = logmap0(hnn1(proj(expmap0(logmap0(x))))) ----
__global__ __launch_bounds__(256) void g_kernel(const float* __restrict__ xin,
                                                const float* __restrict__ W1,
                                                const float* __restrict__ b1,
                                                float* __restrict__ g) {
    int wave = (blockIdx.x * blockDim.x + threadIdx.x) >> 6;
    int lane = threadIdx.x & 63;
    if (wave >= BB * NN) return;
    bool j2ok = lane < (H1 - 128);  // lane < 32 handles third chunk

    // --- load agent row (lanes 0..31 hold components) ---
    float x = (lane < DD) ? xin[wave * DD + lane] : 0.f;

    // feats = logmap0(x)
    float n = fmaxf(sqrtf(wave_sum(x * x)), MINN);
    float f = (artanh_f(n) / n) * x;
    // p = expmap0(feats)
    float fn = fmaxf(sqrtf(wave_sum(f * f)), MINN);
    float p = (tanhf(fn) / fn) * f;
    // proj
    float pn = fmaxf(sqrtf(wave_sum(p * p)), MINN);
    if (pn > MAXNORM) p *= MAXNORM / pn;
    // xn for mobius_matvec
    float xn = fmaxf(sqrtf(wave_sum(p * p)), MINN);

    // mx = W1 @ p  (each lane: rows lane, lane+64, lane+128)
    float mx0 = 0.f, mx1 = 0.f, mx2 = 0.f;
#pragma unroll
    for (int d = 0; d < DD; ++d) {
        float pd = __shfl(p, d, 64);
        mx0 += W1[lane * DD + d] * pd;
        mx1 += W1[(lane + 64) * DD + d] * pd;
        if (j2ok) mx2 += W1[(lane + 128) * DD + d] * pd;
    }
    float m2 = mx0 * mx0 + mx1 * mx1 + (j2ok ? mx2 * mx2 : 0.f);
    float mxn = fmaxf(sqrtf(wave_sum(m2)), MINN);
    float sc = tanhf(mxn / xn * artanh_f(xn)) / mxn;
    float r0 = sc * mx0, r1 = sc * mx1, r2 = sc * mx2;
    // proj
    float rn = fmaxf(sqrtf(wave_sum(r0 * r0 + r1 * r1 + (j2ok ? r2 * r2 : 0.f))), MINN);
    if (rn > MAXNORM) { float s = MAXNORM / rn; r0 *= s; r1 *= s; r2 *= s; }

    // hb = proj(expmap0(b1))  (b1 == 0 in practice; general path kept)
    float bb0 = b1[lane], bb1 = b1[lane + 64], bb2 = j2ok ? b1[lane + 128] : 0.f;
    float bn = fmaxf(sqrtf(wave_sum(bb0 * bb0 + bb1 * bb1 + bb2 * bb2)), MINN);
    float bs = tanhf(bn) / bn;
    float h0 = bs * bb0, h1 = bs * bb1, h2 = bs * bb2;
    float hn = fmaxf(sqrtf(wave_sum(h0 * h0 + h1 * h1 + h2 * h2)), MINN);
    if (hn > MAXNORM) { float s = MAXNORM / hn; h0 *= s; h1 *= s; h2 *= s; }

    // mobius_add(r, h)
    float x2s = wave_sum(r0 * r0 + r1 * r1 + (j2ok ? r2 * r2 : 0.f));
    float y2s = wave_sum(h0 * h0 + h1 * h1 + h2 * h2);
    float xys = wave_sum(r0 * h0 + r1 * h1 + (j2ok ? r2 * h2 : 0.f));
    float ca = 1.f + 2.f * xys + y2s;
    float cb = 1.f - x2s;
    float den = fmaxf(1.f + 2.f * xys + x2s * y2s, MINN);
    float a0 = (ca * r0 + cb * h0) / den;
    float a1 = (ca * r1 + cb * h1) / den;
    float a2 = (ca * r2 + cb * h2) / den;
    // proj
    float an = fmaxf(sqrtf(wave_sum(a0 * a0 + a1 * a1 + (j2ok ? a2 * a2 : 0.f))), MINN);
    if (an > MAXNORM) { float s = MAXNORM / an; a0 *= s; a1 *= s; a2 *= s; }

    // xt = relu(logmap0(a))
    float ln = fmaxf(sqrtf(wave_sum(a0 * a0 + a1 * a1 + (j2ok ? a2 * a2 : 0.f))), MINN);
    float ls = artanh_f(ln) / ln;
    float t0 = fmaxf(ls * a0, 0.f), t1 = fmaxf(ls * a1, 0.f), t2 = fmaxf(ls * a2, 0.f);
    // y = proj(expmap0(xt))
    float tn = fmaxf(sqrtf(wave_sum(t0 * t0 + t1 * t1 + (j2ok ? t2 * t2 : 0.f))), MINN);
    float es = tanhf(tn) / tn;
    float y0 = es * t0, y1 = es * t1, y2 = es * t2;
    float yn = fmaxf(sqrtf(wave_sum(y0 * y0 + y1 * y1 + (j2ok ? y2 * y2 : 0.f))), MINN);
    if (yn > MAXNORM) { float s = MAXNORM / yn; y0 *= s; y1 *= s; y2 *= s; }
    // g = logmap0(y)
    float gn = fmaxf(sqrtf(wave_sum(y0 * y0 + y1 * y1 + (j2ok ? y2 * y2 : 0.f))), MINN);
    float gs = artanh_f(gn) / gn;

    float* go = g + (size_t)wave * H1;
    go[lane] = gs * y0;
    go[lane + 64] = gs * y1;
    if (j2ok) go[lane + 128] = gs * y2;
}

// ---------------- Kernel C1: attention softmax, thread per (b,n,h) ----------
__global__ __launch_bounds__(256) void att_kernel(const float* __restrict__ g,
                                                  const int* __restrict__ idx,
                                                  float* __restrict__ att_out) {
    int t = blockIdx.x * blockDim.x + threadIdx.x;
    if (t >= BB * NN * HEAD) return;
    int h = t % HEAD;
    int r = t / HEAD;   // b*N + n
    int b = r / NN;

    const float* gq = g + (size_t)r * H1;
    float q[HDIM];
#pragma unroll
    for (int d = 0; d < HDIM; ++d) q[d] = gq[d * HEAD + h];

    float s[KK];
#pragma unroll
    for (int k = 0; k < KK; ++k) {
        int m = idx[r * KK + k];
        const float* gk = g + (size_t)(b * NN + m) * H1;
        float acc = 0.f;
#pragma unroll
        for (int d = 0; d < HDIM; ++d) acc += q[d] * gk[d * HEAD + h];
        s[k] = acc;
    }
    float mxv = s[0];
#pragma unroll
    for (int k = 1; k < KK; ++k) mxv = fmaxf(mxv, s[k]);
    float e[KK], sum = 0.f;
#pragma unroll
    for (int k = 0; k < KK; ++k) { e[k] = expf(s[k] - mxv); sum += e[k]; }
    float inv = 1.f / sum;
#pragma unroll
    for (int k = 0; k < KK; ++k) att_out[t * KK + k] = e[k] * inv;
}

// ---------------- Kernel C2: weighted sum + final hnn layer, thread per (b,n) ----
__global__ __launch_bounds__(256) void out_kernel(const float* __restrict__ g,
                                                  const int* __restrict__ idx,
                                                  const float* __restrict__ att,
                                                  const float* __restrict__ W2,
                                                  const float* __restrict__ b2,
                                                  float* __restrict__ out) {
    int r = blockIdx.x * blockDim.x + threadIdx.x;
    if (r >= BB * NN) return;
    int b = r / NN;

    float o[HDIM];
#pragma unroll
    for (int d = 0; d < HDIM; ++d) o[d] = 0.f;
#pragma unroll
    for (int k = 0; k < KK; ++k) {
        int m = idx[r * KK + k];
        const float* gk = g + (size_t)(b * NN + m) * H1;
#pragma unroll
        for (int h = 0; h < HEAD; ++h) {
            float a = att[(r * HEAD + h) * KK + k];
#pragma unroll
            for (int d = 0; d < HDIM; ++d) o[d] += a * gk[d * HEAD + h];
        }
    }
#pragma unroll
    for (int d = 0; d < HDIM; ++d) o[d] *= (1.f / HEAD);

    // proj(expmap0(o))
    float n2 = 0.f;
#pragma unroll
    for (int d = 0; d < HDIM; ++d) n2 += o[d] * o[d];
    float n = fmaxf(sqrtf(n2), MINN);
    float es = tanhf(n) / n;
#pragma unroll
    for (int d = 0; d < HDIM; ++d) o[d] *= es;
    n2 = 0.f;
#pragma unroll
    for (int d = 0; d < HDIM; ++d) n2 += o[d] * o[d];
    n = fmaxf(sqrtf(n2), MINN);
    if (n > MAXNORM) {
        float s = MAXNORM / n;
#pragma unroll
        for (int d = 0; d < HDIM; ++d) o[d] *= s;
    }

    // ---- hnn_layer(o, W2, b2): mobius_matvec ----
    float xn2 = 0.f;
#pragma unroll
    for (int d = 0; d < HDIM; ++d) xn2 += o[d] * o[d];
    float xn = fmaxf(sqrtf(xn2), MINN);
    float mx[HDIM];
#pragma unroll
    for (int j = 0; j < HDIM; ++j) {
        float acc = 0.f;
#pragma unroll
        for (int d = 0; d < HDIM; ++d) acc += W2[j * HDIM + d] * o[d];
        mx[j] = acc;
    }
    float mxn2 = 0.f;
#pragma unroll
    for (int j = 0; j < HDIM; ++j) mxn2 += mx[j] * mx[j];
    float mxn = fmaxf(sqrtf(mxn2), MINN);
    float sc = tanhf(mxn / xn * artanh_f(xn)) / mxn;
#pragma unroll
    for (int j = 0; j < HDIM; ++j) mx[j] *= sc;
    // proj
    float rn2 = 0.f;
#pragma unroll
    for (int j = 0; j < HDIM; ++j) rn2 += mx[j] * mx[j];
    float rn = fmaxf(sqrtf(rn2), MINN);
    if (rn > MAXNORM) {
        float s = MAXNORM / rn;
#pragma unroll
        for (int j = 0; j < HDIM; ++j) mx[j] *= s;
    }

    // hb = proj(expmap0(b2)); mobius_add(mx, hb)
    float hb[HDIM];
    float bn2 = 0.f;
#pragma unroll
    for (int j = 0; j < HDIM; ++j) { hb[j] = b2[j]; bn2 += hb[j] * hb[j]; }
    float bn = fmaxf(sqrtf(bn2), MINN);
    float bs = tanhf(bn) / bn;
    float hn2 = 0.f;
#pragma unroll
    for (int j = 0; j < HDIM; ++j) { hb[j] *= bs; hn2 += hb[j] * hb[j]; }
    float hn = fmaxf(sqrtf(hn2), MINN);
    if (hn > MAXNORM) {
        float s = MAXNORM / hn;
#pragma unroll
        for (int j = 0; j < HDIM; ++j) hb[j] *= s;
    }
    float x2s = 0.f, y2s = 0.f, xys = 0.f;
#pragma unroll
    for (int j = 0; j < HDIM; ++j) {
        x2s += mx[j] * mx[j];
        y2s += hb[j] * hb[j];
        xys += mx[j] * hb[j];
    }
    float ca = 1.f + 2.f * xys + y2s;
    float cb = 1.f - x2s;
    float den = fmaxf(1.f + 2.f * xys + x2s * y2s, MINN);
    float a[HDIM];
#pragma unroll
    for (int j = 0; j < HDIM; ++j) a[j] = (ca * mx[j] + cb * hb[j]) / den;
    float an2 = 0.f;
#pragma unroll
    for (int j = 0; j < HDIM; ++j) an2 += a[j] * a[j];
    float an = fmaxf(sqrtf(an2), MINN);
    if (an > MAXNORM) {
        float s = MAXNORM / an;
#pragma unroll
        for (int j = 0; j < HDIM; ++j) a[j] *= s;
    }
    // xt = relu(logmap0(a))
    float ln2 = 0.f;
#pragma unroll
    for (int j = 0; j < HDIM; ++j) ln2 += a[j] * a[j];
    float lnn = fmaxf(sqrtf(ln2), MINN);
    float ls = artanh_f(lnn) / lnn;
#pragma unroll
    for (int j = 0; j < HDIM; ++j) a[j] = fmaxf(ls * a[j], 0.f);
    // proj(expmap0(xt))
    float tn2 = 0.f;
#pragma unroll
    for (int j = 0; j < HDIM; ++j) tn2 += a[j] * a[j];
    float tn = fmaxf(sqrtf(tn2), MINN);
    float es2 = tanhf(tn) / tn;
#pragma unroll
    for (int j = 0; j < HDIM; ++j) a[j] *= es2;
    float yn2 = 0.f;
#pragma unroll
    for (int j = 0; j < HDIM; ++j) yn2 += a[j] * a[j];
    float yn = fmaxf(sqrtf(yn2), MINN);
    if (yn > MAXNORM) {
        float s = MAXNORM / yn;
#pragma unroll
        for (int j = 0; j < HDIM; ++j) a[j] *= s;
    }
#pragma unroll
    for (int j = 0; j < HDIM; ++j) out[(size_t)r * HDIM + j] = a[j];
}

extern "C" void kernel_launch(void* const* d_in, const int* in_sizes, int n_in,
                              void* d_out, int out_size, void* d_ws, size_t ws_size,
                              hipStream_t stream) {
    const float* in_feats = (const float*)d_in[0];
    const float* in_nei = (const float*)d_in[1];
    const float* W1 = (const float*)d_in[2];
    const float* b1 = (const float*)d_in[3];
    const float* W2 = (const float*)d_in[4];
    const float* b2 = (const float*)d_in[5];

    // workspace layout: idx[40000] ints, then g[8000*160] floats
    int* idx = (int*)d_ws;
    size_t idx_bytes = ((size_t)BB * NN * KK * sizeof(int) + 255) & ~(size_t)255;
    float* g = (float*)((char*)d_ws + idx_bytes);

    float* out = (float*)d_out;                      // [B,N,32] = 256000 floats
    float* att = out + (size_t)BB * NN * HDIM;       // [B,N,head,K] = 200000 floats

    hipLaunchKernelGGL(find_idx_kernel, dim3(4096), dim3(256), 0, stream, in_nei, idx);
    hipLaunchKernelGGL(g_kernel, dim3((BB * NN * 64 + 255) / 256), dim3(256), 0, stream,
                       in_feats, W1, b1, g);
    hipLaunchKernelGGL(att_kernel, dim3((BB * NN * HEAD + 255) / 256), dim3(256), 0, stream,
                       g, idx, att);
    hipLaunchKernelGGL(out_kernel, dim3((BB * NN + 255) / 256), dim3(256), 0, stream,
                       g, idx, att, W2, b2, out);
}

// Round 2
// 520.832 us; speedup vs baseline: 1.1420x; 1.1420x over previous
//
#include <hip/hip_runtime.h>
#include <math.h>

#define BB 4
#define NN 2000
#define KK 5
#define DD 32
#define H1 160
#define HEAD 5
#define HDIM 32
#define MAXNORM 0.996f
#define MINN 1e-15f

__device__ __forceinline__ float artanh_f(float x) {
    x = fminf(fmaxf(x, -1.0f + 1e-7f), 1.0f - 1e-7f);
    return 0.5f * (log1pf(x) - log1pf(-x));
}

// sum over a full 64-lane wave
__device__ __forceinline__ float wave_sum(float v) {
#pragma unroll
    for (int o = 32; o > 0; o >>= 1) v += __shfl_xor(v, o, 64);
    return v;
}

// sum within each 32-lane half (both halves hold identical data in our usage)
__device__ __forceinline__ float wave_sum32(float v) {
#pragma unroll
    for (int o = 16; o > 0; o >>= 1) v += __shfl_xor(v, o, 64);
    return v;
}

// ---------------- Kernel A: early-exit one-hot search, wave per row ---------
__global__ __launch_bounds__(256) void find_idx_kernel(const float* __restrict__ nei,
                                                       int* __restrict__ idx) {
    int wave = (blockIdx.x * blockDim.x + threadIdx.x) >> 6;
    int lane = threadIdx.x & 63;
    if (wave >= BB * NN * KK) return;
    const float* row = nei + (size_t)wave * NN;
#pragma unroll 1
    for (int it = 0; it < 8; ++it) {
        int base = it * 256 + lane * 4;
        bool found = false;
        int pos = 0;
        if (base < NN) {  // NN divisible by 4, base multiple of 4 -> float4 safe
            float4 v = *(const float4*)(row + base);
            if (v.x > 0.5f) { found = true; pos = base; }
            if (v.y > 0.5f) { found = true; pos = base + 1; }
            if (v.z > 0.5f) { found = true; pos = base + 2; }
            if (v.w > 0.5f) { found = true; pos = base + 3; }
        }
        unsigned long long m = __ballot(found);
        if (m) {
            if (found) idx[wave] = pos;
            break;
        }
    }
}

// ---------------- Kernel B: g[b*N+n, 0:160] = logmap0(hnn1(proj(expmap0(logmap0(x))))) ----
__global__ __launch_bounds__(256) void g_kernel(const float* __restrict__ xin,
                                                const float* __restrict__ W1,
                                                const float* __restrict__ b1,
                                                float* __restrict__ g) {
    int wave = (blockIdx.x * blockDim.x + threadIdx.x) >> 6;
    int lane = threadIdx.x & 63;
    if (wave >= BB * NN) return;
    bool j2ok = lane < (H1 - 128);  // lane < 32 handles third chunk

    // --- load agent row (lanes 0..31 hold components) ---
    float x = (lane < DD) ? xin[wave * DD + lane] : 0.f;

    // feats = logmap0(x)
    float n = fmaxf(sqrtf(wave_sum(x * x)), MINN);
    float f = (artanh_f(n) / n) * x;
    // p = expmap0(feats)
    float fn = fmaxf(sqrtf(wave_sum(f * f)), MINN);
    float p = (tanhf(fn) / fn) * f;
    // proj
    float pn = fmaxf(sqrtf(wave_sum(p * p)), MINN);
    if (pn > MAXNORM) p *= MAXNORM / pn;
    // xn for mobius_matvec
    float xn = fmaxf(sqrtf(wave_sum(p * p)), MINN);

    // mx = W1 @ p  (each lane: rows lane, lane+64, lane+128)
    float mx0 = 0.f, mx1 = 0.f, mx2 = 0.f;
#pragma unroll
    for (int d = 0; d < DD; ++d) {
        float pd = __shfl(p, d, 64);
        mx0 += W1[lane * DD + d] * pd;
        mx1 += W1[(lane + 64) * DD + d] * pd;
        if (j2ok) mx2 += W1[(lane + 128) * DD + d] * pd;
    }
    float m2 = mx0 * mx0 + mx1 * mx1 + (j2ok ? mx2 * mx2 : 0.f);
    float mxn = fmaxf(sqrtf(wave_sum(m2)), MINN);
    float sc = tanhf(mxn / xn * artanh_f(xn)) / mxn;
    float r0 = sc * mx0, r1 = sc * mx1, r2 = sc * mx2;
    // proj
    float rn = fmaxf(sqrtf(wave_sum(r0 * r0 + r1 * r1 + (j2ok ? r2 * r2 : 0.f))), MINN);
    if (rn > MAXNORM) { float s = MAXNORM / rn; r0 *= s; r1 *= s; r2 *= s; }

    // hb = proj(expmap0(b1))  (b1 == 0 in practice; general path kept)
    float bb0 = b1[lane], bb1 = b1[lane + 64], bb2 = j2ok ? b1[lane + 128] : 0.f;
    float bn = fmaxf(sqrtf(wave_sum(bb0 * bb0 + bb1 * bb1 + bb2 * bb2)), MINN);
    float bs = tanhf(bn) / bn;
    float h0 = bs * bb0, h1 = bs * bb1, h2 = bs * bb2;
    float hn = fmaxf(sqrtf(wave_sum(h0 * h0 + h1 * h1 + h2 * h2)), MINN);
    if (hn > MAXNORM) { float s = MAXNORM / hn; h0 *= s; h1 *= s; h2 *= s; }

    // mobius_add(r, h)
    float x2s = wave_sum(r0 * r0 + r1 * r1 + (j2ok ? r2 * r2 : 0.f));
    float y2s = wave_sum(h0 * h0 + h1 * h1 + h2 * h2);
    float xys = wave_sum(r0 * h0 + r1 * h1 + (j2ok ? r2 * h2 : 0.f));
    float ca = 1.f + 2.f * xys + y2s;
    float cb = 1.f - x2s;
    float den = fmaxf(1.f + 2.f * xys + x2s * y2s, MINN);
    float a0 = (ca * r0 + cb * h0) / den;
    float a1 = (ca * r1 + cb * h1) / den;
    float a2 = (ca * r2 + cb * h2) / den;
    // proj
    float an = fmaxf(sqrtf(wave_sum(a0 * a0 + a1 * a1 + (j2ok ? a2 * a2 : 0.f))), MINN);
    if (an > MAXNORM) { float s = MAXNORM / an; a0 *= s; a1 *= s; a2 *= s; }

    // xt = relu(logmap0(a))
    float ln = fmaxf(sqrtf(wave_sum(a0 * a0 + a1 * a1 + (j2ok ? a2 * a2 : 0.f))), MINN);
    float ls = artanh_f(ln) / ln;
    float t0 = fmaxf(ls * a0, 0.f), t1 = fmaxf(ls * a1, 0.f), t2 = fmaxf(ls * a2, 0.f);
    // y = proj(expmap0(xt))
    float tn = fmaxf(sqrtf(wave_sum(t0 * t0 + t1 * t1 + (j2ok ? t2 * t2 : 0.f))), MINN);
    float es = tanhf(tn) / tn;
    float y0 = es * t0, y1 = es * t1, y2 = es * t2;
    float yn = fmaxf(sqrtf(wave_sum(y0 * y0 + y1 * y1 + (j2ok ? y2 * y2 : 0.f))), MINN);
    if (yn > MAXNORM) { float s = MAXNORM / yn; y0 *= s; y1 *= s; y2 *= s; }
    // g = logmap0(y)
    float gn = fmaxf(sqrtf(wave_sum(y0 * y0 + y1 * y1 + (j2ok ? y2 * y2 : 0.f))), MINN);
    float gs = artanh_f(gn) / gn;

    float* go = g + (size_t)wave * H1;
    go[lane] = gs * y0;
    go[lane + 64] = gs * y1;
    if (j2ok) go[lane + 128] = gs * y2;
}

// ---------------- Kernel C: fused attention + output layer, wave per (b,n) --
__global__ __launch_bounds__(256) void fused_att_out_kernel(const float* __restrict__ g,
                                                            const int* __restrict__ idx,
                                                            const float* __restrict__ W2,
                                                            const float* __restrict__ b2,
                                                            float* __restrict__ out,
                                                            float* __restrict__ att_out) {
    int wave = (blockIdx.x * blockDim.x + threadIdx.x) >> 6;
    int lane = threadIdx.x & 63;
    if (wave >= BB * NN) return;
    int r = wave;
    int b = r / NN;
    int d = lane & 31;  // both 32-halves do identical work

    // q[d][h]
    const float* gq = g + (size_t)r * H1;
    float q[HEAD];
#pragma unroll
    for (int h = 0; h < HEAD; ++h) q[h] = gq[d * HEAD + h];

    // kv[k][d][h] and scores s[k][h] = sum_d q*kv (shuffle-reduced, broadcast)
    float kv[KK][HEAD];
    float s[KK][HEAD];
#pragma unroll
    for (int k = 0; k < KK; ++k) {
        int m = idx[r * KK + k];
        const float* gk = g + (size_t)(b * NN + m) * H1;
#pragma unroll
        for (int h = 0; h < HEAD; ++h) kv[k][h] = gk[d * HEAD + h];
#pragma unroll
        for (int h = 0; h < HEAD; ++h) s[k][h] = wave_sum32(q[h] * kv[k][h]);
    }

    // softmax over k per head (redundant per lane; all lanes hold s)
    float att[HEAD][KK];
#pragma unroll
    for (int h = 0; h < HEAD; ++h) {
        float mxv = s[0][h];
#pragma unroll
        for (int k = 1; k < KK; ++k) mxv = fmaxf(mxv, s[k][h]);
        float sum = 0.f;
#pragma unroll
        for (int k = 0; k < KK; ++k) { att[h][k] = expf(s[k][h] - mxv); sum += att[h][k]; }
        float inv = 1.f / sum;
#pragma unroll
        for (int k = 0; k < KK; ++k) att[h][k] *= inv;
    }
    // att_record: [r][h][k], lanes 0..24 write
    if (lane < HEAD * KK) {
        int h = lane / KK, k = lane % KK;
        att_out[(size_t)r * HEAD * KK + lane] = att[h][k];
    }

    // o[d] = mean over heads of sum_k att*kv
    float o = 0.f;
#pragma unroll
    for (int h = 0; h < HEAD; ++h)
#pragma unroll
        for (int k = 0; k < KK; ++k) o += att[h][k] * kv[k][h];
    o *= (1.f / HEAD);

    // ---- proj(expmap0(o)) ----
    float n = fmaxf(sqrtf(wave_sum32(o * o)), MINN);
    o *= tanhf(n) / n;
    n = fmaxf(sqrtf(wave_sum32(o * o)), MINN);
    if (n > MAXNORM) o *= MAXNORM / n;

    // ---- hnn_layer(o, W2, b2) ----
    float xn = fmaxf(sqrtf(wave_sum32(o * o)), MINN);
    // mx[j] = W2[j,:] @ o  (j = lane&31)
    float mx = 0.f;
#pragma unroll
    for (int dd = 0; dd < HDIM; ++dd) {
        float od = __shfl(o, dd, 64);
        mx += W2[d * HDIM + dd] * od;
    }
    float mxn = fmaxf(sqrtf(wave_sum32(mx * mx)), MINN);
    float sc = tanhf(mxn / xn * artanh_f(xn)) / mxn;
    mx *= sc;
    // proj
    float rn = fmaxf(sqrtf(wave_sum32(mx * mx)), MINN);
    if (rn > MAXNORM) mx *= MAXNORM / rn;

    // hb = proj(expmap0(b2))
    float hb = b2[d];
    float bn = fmaxf(sqrtf(wave_sum32(hb * hb)), MINN);
    hb *= tanhf(bn) / bn;
    float hn = fmaxf(sqrtf(wave_sum32(hb * hb)), MINN);
    if (hn > MAXNORM) hb *= MAXNORM / hn;

    // mobius_add(mx, hb)
    float x2s = wave_sum32(mx * mx);
    float y2s = wave_sum32(hb * hb);
    float xys = wave_sum32(mx * hb);
    float ca = 1.f + 2.f * xys + y2s;
    float cb = 1.f - x2s;
    float den = fmaxf(1.f + 2.f * xys + x2s * y2s, MINN);
    float a = (ca * mx + cb * hb) / den;
    // proj
    float an = fmaxf(sqrtf(wave_sum32(a * a)), MINN);
    if (an > MAXNORM) a *= MAXNORM / an;

    // xt = relu(logmap0(a))
    float ln = fmaxf(sqrtf(wave_sum32(a * a)), MINN);
    a = fmaxf((artanh_f(ln) / ln) * a, 0.f);
    // proj(expmap0(xt))
    float tn = fmaxf(sqrtf(wave_sum32(a * a)), MINN);
    a *= tanhf(tn) / tn;
    float yn = fmaxf(sqrtf(wave_sum32(a * a)), MINN);
    if (yn > MAXNORM) a *= MAXNORM / yn;

    if (lane < HDIM) out[(size_t)r * HDIM + lane] = a;
}

extern "C" void kernel_launch(void* const* d_in, const int* in_sizes, int n_in,
                              void* d_out, int out_size, void* d_ws, size_t ws_size,
                              hipStream_t stream) {
    const float* in_feats = (const float*)d_in[0];
    const float* in_nei = (const float*)d_in[1];
    const float* W1 = (const float*)d_in[2];
    const float* b1 = (const float*)d_in[3];
    const float* W2 = (const float*)d_in[4];
    const float* b2 = (const float*)d_in[5];

    // workspace layout: idx[40000] ints, then g[8000*160] floats
    int* idx = (int*)d_ws;
    size_t idx_bytes = ((size_t)BB * NN * KK * sizeof(int) + 255) & ~(size_t)255;
    float* g = (float*)((char*)d_ws + idx_bytes);

    float* out = (float*)d_out;                      // [B,N,32] = 256000 floats
    float* att = out + (size_t)BB * NN * HDIM;       // [B,N,head,K] = 200000 floats

    // A: wave per one-hot row: 40000 waves -> 10000 blocks of 256
    hipLaunchKernelGGL(find_idx_kernel, dim3(BB * NN * KK * 64 / 256), dim3(256), 0, stream,
                       in_nei, idx);
    // B: wave per (b,n): 8000 waves -> 2000 blocks
    hipLaunchKernelGGL(g_kernel, dim3((BB * NN * 64 + 255) / 256), dim3(256), 0, stream,
                       in_feats, W1, b1, g);
    // C: fused attention + output layer, wave per (b,n)
    hipLaunchKernelGGL(fused_att_out_kernel, dim3((BB * NN * 64 + 255) / 256), dim3(256), 0, stream,
                       g, idx, W2, b2, out, att);
}

// Round 3
// 515.227 us; speedup vs baseline: 1.1545x; 1.0109x over previous
//
#include <hip/hip_runtime.h>
#include <math.h>

#define BB 4
#define NN 2000
#define KK 5
#define DD 32
#define H1 160
#define HEAD 5
#define HDIM 32
#define MAXNORM 0.996f
#define MINN 1e-15f

#define NIDX_BLOCKS 10000   // 40000 one-hot rows, 4 waves/block
#define NG_BLOCKS 2000      // 8000 g-rows, 4 waves/block

__device__ __forceinline__ float artanh_f(float x) {
    x = fminf(fmaxf(x, -1.0f + 1e-7f), 1.0f - 1e-7f);
    return 0.5f * (log1pf(x) - log1pf(-x));
}

// sum over a full 64-lane wave
__device__ __forceinline__ float wave_sum(float v) {
#pragma unroll
    for (int o = 32; o > 0; o >>= 1) v += __shfl_xor(v, o, 64);
    return v;
}

// sum within each 32-lane half (both halves hold identical data in our usage)
__device__ __forceinline__ float wave_sum32(float v) {
#pragma unroll
    for (int o = 16; o > 0; o >>= 1) v += __shfl_xor(v, o, 64);
    return v;
}

// ---------------- find_idx work: early-exit one-hot search, wave per row ----
__device__ __forceinline__ void do_find_idx(const float* __restrict__ nei,
                                            int* __restrict__ idx,
                                            int wave, int lane) {
    const float* row = nei + (size_t)wave * NN;
#pragma unroll 1
    for (int it = 0; it < 8; ++it) {
        int base = it * 256 + lane * 4;
        bool found = false;
        int pos = 0;
        if (base < NN) {  // NN divisible by 4, base multiple of 4 -> float4 safe
            float4 v = *(const float4*)(row + base);
            if (v.x > 0.5f) { found = true; pos = base; }
            if (v.y > 0.5f) { found = true; pos = base + 1; }
            if (v.z > 0.5f) { found = true; pos = base + 2; }
            if (v.w > 0.5f) { found = true; pos = base + 3; }
        }
        unsigned long long m = __ballot(found);
        if (m) {
            if (found) idx[wave] = pos;
            break;
        }
    }
}

// ---------------- g work: g[row,0:160] = logmap0(hnn1(proj(expmap0(logmap0(x))))) ----
__device__ __forceinline__ void do_g(const float* __restrict__ xin,
                                     const float* __restrict__ W1,
                                     const float* __restrict__ b1,
                                     float* __restrict__ g,
                                     int wave, int lane) {
    bool j2ok = lane < (H1 - 128);  // lane < 32 handles third chunk

    // --- load agent row (lanes 0..31 hold components) ---
    float x = (lane < DD) ? xin[wave * DD + lane] : 0.f;

    // feats = logmap0(x)
    float n = fmaxf(sqrtf(wave_sum(x * x)), MINN);
    float f = (artanh_f(n) / n) * x;
    // p = expmap0(feats)
    float fn = fmaxf(sqrtf(wave_sum(f * f)), MINN);
    float p = (tanhf(fn) / fn) * f;
    // proj
    float pn = fmaxf(sqrtf(wave_sum(p * p)), MINN);
    if (pn > MAXNORM) p *= MAXNORM / pn;
    // xn for mobius_matvec
    float xn = fmaxf(sqrtf(wave_sum(p * p)), MINN);

    // mx = W1 @ p  (each lane: rows lane, lane+64, lane+128)
    float mx0 = 0.f, mx1 = 0.f, mx2 = 0.f;
#pragma unroll
    for (int d = 0; d < DD; ++d) {
        float pd = __shfl(p, d, 64);
        mx0 += W1[lane * DD + d] * pd;
        mx1 += W1[(lane + 64) * DD + d] * pd;
        if (j2ok) mx2 += W1[(lane + 128) * DD + d] * pd;
    }
    float m2 = mx0 * mx0 + mx1 * mx1 + (j2ok ? mx2 * mx2 : 0.f);
    float mxn = fmaxf(sqrtf(wave_sum(m2)), MINN);
    float sc = tanhf(mxn / xn * artanh_f(xn)) / mxn;
    float r0 = sc * mx0, r1 = sc * mx1, r2 = sc * mx2;
    // proj
    float rn = fmaxf(sqrtf(wave_sum(r0 * r0 + r1 * r1 + (j2ok ? r2 * r2 : 0.f))), MINN);
    if (rn > MAXNORM) { float s = MAXNORM / rn; r0 *= s; r1 *= s; r2 *= s; }

    // hb = proj(expmap0(b1))  (b1 == 0 in practice; general path kept)
    float bb0 = b1[lane], bb1 = b1[lane + 64], bb2 = j2ok ? b1[lane + 128] : 0.f;
    float bn = fmaxf(sqrtf(wave_sum(bb0 * bb0 + bb1 * bb1 + bb2 * bb2)), MINN);
    float bs = tanhf(bn) / bn;
    float h0 = bs * bb0, h1 = bs * bb1, h2 = bs * bb2;
    float hn = fmaxf(sqrtf(wave_sum(h0 * h0 + h1 * h1 + h2 * h2)), MINN);
    if (hn > MAXNORM) { float s = MAXNORM / hn; h0 *= s; h1 *= s; h2 *= s; }

    // mobius_add(r, h)
    float x2s = wave_sum(r0 * r0 + r1 * r1 + (j2ok ? r2 * r2 : 0.f));
    float y2s = wave_sum(h0 * h0 + h1 * h1 + h2 * h2);
    float xys = wave_sum(r0 * h0 + r1 * h1 + (j2ok ? r2 * h2 : 0.f));
    float ca = 1.f + 2.f * xys + y2s;
    float cb = 1.f - x2s;
    float den = fmaxf(1.f + 2.f * xys + x2s * y2s, MINN);
    float a0 = (ca * r0 + cb * h0) / den;
    float a1 = (ca * r1 + cb * h1) / den;
    float a2 = (ca * r2 + cb * h2) / den;
    // proj
    float an = fmaxf(sqrtf(wave_sum(a0 * a0 + a1 * a1 + (j2ok ? a2 * a2 : 0.f))), MINN);
    if (an > MAXNORM) { float s = MAXNORM / an; a0 *= s; a1 *= s; a2 *= s; }

    // xt = relu(logmap0(a))
    float ln = fmaxf(sqrtf(wave_sum(a0 * a0 + a1 * a1 + (j2ok ? a2 * a2 : 0.f))), MINN);
    float ls = artanh_f(ln) / ln;
    float t0 = fmaxf(ls * a0, 0.f), t1 = fmaxf(ls * a1, 0.f), t2 = fmaxf(ls * a2, 0.f);
    // y = proj(expmap0(xt))
    float tn = fmaxf(sqrtf(wave_sum(t0 * t0 + t1 * t1 + (j2ok ? t2 * t2 : 0.f))), MINN);
    float es = tanhf(tn) / tn;
    float y0 = es * t0, y1 = es * t1, y2 = es * t2;
    float yn = fmaxf(sqrtf(wave_sum(y0 * y0 + y1 * y1 + (j2ok ? y2 * y2 : 0.f))), MINN);
    if (yn > MAXNORM) { float s = MAXNORM / yn; y0 *= s; y1 *= s; y2 *= s; }
    // g = logmap0(y)
    float gn = fmaxf(sqrtf(wave_sum(y0 * y0 + y1 * y1 + (j2ok ? y2 * y2 : 0.f))), MINN);
    float gs = artanh_f(gn) / gn;

    float* go = g + (size_t)wave * H1;
    go[lane] = gs * y0;
    go[lane + 64] = gs * y1;
    if (j2ok) go[lane + 128] = gs * y2;
}

// ---------------- Kernel 1: heterogeneous grid — scan (HBM-bound) ∥ g (VALU-bound) ----
__global__ __launch_bounds__(256) void scan_and_g_kernel(const float* __restrict__ nei,
                                                         int* __restrict__ idx,
                                                         const float* __restrict__ xin,
                                                         const float* __restrict__ W1,
                                                         const float* __restrict__ b1,
                                                         float* __restrict__ g) {
    int lane = threadIdx.x & 63;
    int waveInBlock = threadIdx.x >> 6;
    if (blockIdx.x < NIDX_BLOCKS) {
        int wave = blockIdx.x * 4 + waveInBlock;   // 0..39999
        do_find_idx(nei, idx, wave, lane);
    } else {
        int wave = (blockIdx.x - NIDX_BLOCKS) * 4 + waveInBlock;  // 0..7999
        do_g(xin, W1, b1, g, wave, lane);
    }
}

// ---------------- Kernel 2: fused attention + output layer, wave per (b,n) --
__global__ __launch_bounds__(256) void fused_att_out_kernel(const float* __restrict__ g,
                                                            const int* __restrict__ idx,
                                                            const float* __restrict__ W2,
                                                            const float* __restrict__ b2,
                                                            float* __restrict__ out,
                                                            float* __restrict__ att_out) {
    int wave = (blockIdx.x * blockDim.x + threadIdx.x) >> 6;
    int lane = threadIdx.x & 63;
    if (wave >= BB * NN) return;
    int r = wave;
    int b = r / NN;
    int d = lane & 31;  // both 32-halves do identical work

    // q[d][h]
    const float* gq = g + (size_t)r * H1;
    float q[HEAD];
#pragma unroll
    for (int h = 0; h < HEAD; ++h) q[h] = gq[d * HEAD + h];

    // kv[k][d][h] and scores s[k][h] = sum_d q*kv (shuffle-reduced, broadcast)
    float kv[KK][HEAD];
    float s[KK][HEAD];
#pragma unroll
    for (int k = 0; k < KK; ++k) {
        int m = idx[r * KK + k];
        const float* gk = g + (size_t)(b * NN + m) * H1;
#pragma unroll
        for (int h = 0; h < HEAD; ++h) kv[k][h] = gk[d * HEAD + h];
#pragma unroll
        for (int h = 0; h < HEAD; ++h) s[k][h] = wave_sum32(q[h] * kv[k][h]);
    }

    // softmax over k per head (redundant per lane; all lanes hold s)
    float att[HEAD][KK];
#pragma unroll
    for (int h = 0; h < HEAD; ++h) {
        float mxv = s[0][h];
#pragma unroll
        for (int k = 1; k < KK; ++k) mxv = fmaxf(mxv, s[k][h]);
        float sum = 0.f;
#pragma unroll
        for (int k = 0; k < KK; ++k) { att[h][k] = expf(s[k][h] - mxv); sum += att[h][k]; }
        float inv = 1.f / sum;
#pragma unroll
        for (int k = 0; k < KK; ++k) att[h][k] *= inv;
    }
    // att_record: [r][h][k], lanes 0..24 write
    if (lane < HEAD * KK) {
        int h = lane / KK, k = lane % KK;
        att_out[(size_t)r * HEAD * KK + lane] = att[h][k];
    }

    // o[d] = mean over heads of sum_k att*kv
    float o = 0.f;
#pragma unroll
    for (int h = 0; h < HEAD; ++h)
#pragma unroll
        for (int k = 0; k < KK; ++k) o += att[h][k] * kv[k][h];
    o *= (1.f / HEAD);

    // ---- proj(expmap0(o)) ----
    float n = fmaxf(sqrtf(wave_sum32(o * o)), MINN);
    o *= tanhf(n) / n;
    n = fmaxf(sqrtf(wave_sum32(o * o)), MINN);
    if (n > MAXNORM) o *= MAXNORM / n;

    // ---- hnn_layer(o, W2, b2) ----
    float xn = fmaxf(sqrtf(wave_sum32(o * o)), MINN);
    // mx[j] = W2[j,:] @ o  (j = lane&31)
    float mx = 0.f;
#pragma unroll
    for (int dd = 0; dd < HDIM; ++dd) {
        float od = __shfl(o, dd, 64);
        mx += W2[d * HDIM + dd] * od;
    }
    float mxn = fmaxf(sqrtf(wave_sum32(mx * mx)), MINN);
    float sc = tanhf(mxn / xn * artanh_f(xn)) / mxn;
    mx *= sc;
    // proj
    float rn = fmaxf(sqrtf(wave_sum32(mx * mx)), MINN);
    if (rn > MAXNORM) mx *= MAXNORM / rn;

    // hb = proj(expmap0(b2))
    float hb = b2[d];
    float bn = fmaxf(sqrtf(wave_sum32(hb * hb)), MINN);
    hb *= tanhf(bn) / bn;
    float hn = fmaxf(sqrtf(wave_sum32(hb * hb)), MINN);
    if (hn > MAXNORM) hb *= MAXNORM / hn;

    // mobius_add(mx, hb)
    float x2s = wave_sum32(mx * mx);
    float y2s = wave_sum32(hb * hb);
    float xys = wave_sum32(mx * hb);
    float ca = 1.f + 2.f * xys + y2s;
    float cb = 1.f - x2s;
    float den = fmaxf(1.f + 2.f * xys + x2s * y2s, MINN);
    float a = (ca * mx + cb * hb) / den;
    // proj
    float an = fmaxf(sqrtf(wave_sum32(a * a)), MINN);
    if (an > MAXNORM) a *= MAXNORM / an;

    // xt = relu(logmap0(a))
    float ln = fmaxf(sqrtf(wave_sum32(a * a)), MINN);
    a = fmaxf((artanh_f(ln) / ln) * a, 0.f);
    // proj(expmap0(xt))
    float tn = fmaxf(sqrtf(wave_sum32(a * a)), MINN);
    a *= tanhf(tn) / tn;
    float yn = fmaxf(sqrtf(wave_sum32(a * a)), MINN);
    if (yn > MAXNORM) a *= MAXNORM / yn;

    if (lane < HDIM) out[(size_t)r * HDIM + lane] = a;
}

extern "C" void kernel_launch(void* const* d_in, const int* in_sizes, int n_in,
                              void* d_out, int out_size, void* d_ws, size_t ws_size,
                              hipStream_t stream) {
    const float* in_feats = (const float*)d_in[0];
    const float* in_nei = (const float*)d_in[1];
    const float* W1 = (const float*)d_in[2];
    const float* b1 = (const float*)d_in[3];
    const float* W2 = (const float*)d_in[4];
    const float* b2 = (const float*)d_in[5];

    // workspace layout: idx[40000] ints, then g[8000*160] floats
    int* idx = (int*)d_ws;
    size_t idx_bytes = ((size_t)BB * NN * KK * sizeof(int) + 255) & ~(size_t)255;
    float* g = (float*)((char*)d_ws + idx_bytes);

    float* out = (float*)d_out;                      // [B,N,32] = 256000 floats
    float* att = out + (size_t)BB * NN * HDIM;       // [B,N,head,K] = 200000 floats

    // Kernel 1: blocks [0,10000) scan in_nei for one-hot indices (HBM-bound);
    //           blocks [10000,12000) compute g table (VALU-bound). Independent work,
    //           overlapped in one launch.
    hipLaunchKernelGGL(scan_and_g_kernel, dim3(NIDX_BLOCKS + NG_BLOCKS), dim3(256), 0, stream,
                       in_nei, idx, in_feats, W1, b1, g);
    // Kernel 2: fused attention + output layer, wave per (b,n)
    hipLaunchKernelGGL(fused_att_out_kernel, dim3((BB * NN * 64 + 255) / 256), dim3(256), 0, stream,
                       g, idx, W2, b2, out, att);
}